// Round 6
// baseline (46.807 us; speedup 1.0000x reference)
//
#include <hip/hip_runtime.h>

// Resample1d: out[b,c,h,w] = lerp of input1[b,c,h,:] at x = w + disp[b,h,w],
// zeroed where x outside [0, W-1].
// Shapes: input1 (B,C,H,W) f32, input2 (B,1,H,W) f32, out (B,C,H,W) f32.
//
// R6 = R5 + LDS XOR-swizzle s(a)=a^((a>>5)&3) to kill the stride-4 tap
// bank conflicts (4.47M conflict cycles in R5):
//  - read side: swizzled tap addrs si0/si1 hoisted once over all channels
//  - write side: in-register XOR-permute by k=(lane>>3)&3, keeps ds_write_b128
//  - 2-deep prefetch ring, early param issue, dwordx4 NT stores unchanged

#define B 4
#define C 64
#define H 256
#define W 512
#define WAVES 4          // waves per block
#define CPW 8            // channels per wave
// grid = (B*H, C/(WAVES*CPW)) = (1024, 2); block = 256

typedef float f32x4 __attribute__((ext_vector_type(4)));

__device__ __forceinline__ int swz(int a) { return a ^ ((a >> 5) & 3); }

// dest[j] = v[j ^ k], k in 0..3 (per-lane runtime) -> 8 v_cndmask
__device__ __forceinline__ f32x4 xorperm(f32x4 v, int k) {
    bool b0 = (k & 1) != 0;
    f32x4 t;
    t[0] = b0 ? v[1] : v[0];
    t[1] = b0 ? v[0] : v[1];
    t[2] = b0 ? v[3] : v[2];
    t[3] = b0 ? v[2] : v[3];
    bool b1 = (k & 2) != 0;
    f32x4 u;
    u[0] = b1 ? t[2] : t[0];
    u[1] = b1 ? t[3] : t[1];
    u[2] = b1 ? t[0] : t[2];
    u[3] = b1 ? t[1] : t[3];
    return u;
}

__global__ __launch_bounds__(256) void resample1d_kernel(
    const float* __restrict__ in1,   // (B,C,H,W)
    const float* __restrict__ in2,   // (B,1,H,W)
    float* __restrict__ out)         // (B,C,H,W)
{
    __shared__ float rowbuf[WAVES][W];   // 4 x 2KB, wave-private chunks

    const int tid  = threadIdx.x;
    const int wid  = tid >> 6;
    const int lane = tid & 63;
    const int k    = (lane >> 3) & 3;    // write-side XOR-permute key

    const int bh = blockIdx.x;          // 0..B*H-1
    const int b  = bh >> 8;             // / H  (H=256)
    const int cbase = blockIdx.y * (WAVES * CPW) + wid * CPW;

    const size_t chan_stride = (size_t)H * W;
    const float* src = in1 + ((size_t)b * C + cbase) * chan_stride + (size_t)(bh & (H - 1)) * W;
    float*       dst = out + ((size_t)b * C + cbase) * chan_stride + (size_t)(bh & (H - 1)) * W;
    const float* disp_row = in2 + (size_t)bh * W;

    // ---- issue first two channels' loads + disp loads up front ----
    f32x4 pre0[2], pre1[2];             // 2-deep prefetch ring (unrolled -> regs)
    pre0[0] = *(const f32x4*)(src + 4 * lane);
    pre1[0] = *(const f32x4*)(src + 256 + 4 * lane);
    pre0[1] = *(const f32x4*)(src + chan_stride + 4 * lane);
    pre1[1] = *(const f32x4*)(src + chan_stride + 256 + 4 * lane);
    f32x4 d4[2];
    d4[0] = *(const f32x4*)(disp_row + 4 * lane);
    d4[1] = *(const f32x4*)(disp_row + 256 + 4 * lane);

    // ---- per-lane pixel params, SWIZZLED tap addrs (hoisted over c) ----
    int   si0[2][4], si1[2][4];
    float w0[2][4], w1[2][4];
    #pragma unroll
    for (int g = 0; g < 2; ++g) {
        #pragma unroll
        for (int j = 0; j < 4; ++j) {
            int w = 4 * lane + 256 * g + j;
            float x = (float)w + d4[g][j];
            bool valid = (x >= 0.0f) && (x <= (float)(W - 1));
            float x0 = floorf(x);
            float frac = x - x0;
            int a0 = (int)fminf(fmaxf(x0, 0.0f), (float)(W - 1));
            si0[g][j] = swz(a0);
            si1[g][j] = swz(min(a0 + 1, W - 1));
            w0[g][j] = valid ? (1.0f - frac) : 0.0f;
            w1[g][j] = valid ? frac : 0.0f;
        }
    }

    float* rb = rowbuf[wid];

    #pragma unroll
    for (int cc = 0; cc < CPW; ++cc) {
        // staged regs -> wave-private LDS, XOR-permuted to match swizzle
        *(f32x4*)(rb + 4 * lane)       = xorperm(pre0[cc & 1], k);
        *(f32x4*)(rb + 256 + 4 * lane) = xorperm(pre1[cc & 1], k);
        // refill the ring slot just consumed (keeps 4 loads in flight)
        if (cc + 2 < CPW) {
            const float* s2 = src + (size_t)(cc + 2) * chan_stride;
            pre0[cc & 1] = *(const f32x4*)(s2 + 4 * lane);
            pre1[cc & 1] = *(const f32x4*)(s2 + 256 + 4 * lane);
        }
        // taps from swizzled LDS, lerp, two coalesced dwordx4 NT stores
        float* d = dst + (size_t)cc * chan_stride;
        #pragma unroll
        for (int g = 0; g < 2; ++g) {
            f32x4 r;
            #pragma unroll
            for (int j = 0; j < 4; ++j) {
                r[j] = w0[g][j] * rb[si0[g][j]] + w1[g][j] * rb[si1[g][j]];
            }
            __builtin_nontemporal_store(r, (f32x4*)(d + 4 * lane + 256 * g));
        }
    }
}

extern "C" void kernel_launch(void* const* d_in, const int* in_sizes, int n_in,
                              void* d_out, int out_size, void* d_ws, size_t ws_size,
                              hipStream_t stream) {
    const float* in1 = (const float*)d_in[0];
    const float* in2 = (const float*)d_in[1];
    float* out = (float*)d_out;

    dim3 grid(B * H, C / (WAVES * CPW)), block(WAVES * 64);
    resample1d_kernel<<<grid, block, 0, stream>>>(in1, in2, out);
}